// Round 1
// baseline (1045.235 us; speedup 1.0000x reference)
//
#include <hip/hip_runtime.h>

#define BATCH 1024
#define HID 50
#define NT 100
#define SUB 2   // RK4 substeps per output interval

// tanh(x) = 1 - 2/(exp(2x)+1), exp(2x) = exp2(x * 2*log2(e))
// v_exp_f32 + v_rcp_f32: ~1e-7 abs error, correct limits at +/-inf.
__device__ __forceinline__ float fast_tanh(float x) {
    float e = __builtin_amdgcn_exp2f(x * 2.8853900817779268f);
    return 1.0f - 2.0f * __builtin_amdgcn_rcpf(e + 1.0f);
}

__global__ __launch_bounds__(256, 1)
void ode_rk4_kernel(const float* __restrict__ h0,
                    const float* __restrict__ ts,
                    const float* __restrict__ w1,
                    const float* __restrict__ b1,
                    const float* __restrict__ w2,
                    const float* __restrict__ b2,
                    float* __restrict__ out) {
    const int b = blockIdx.x * blockDim.x + threadIdx.x;
    if (b >= BATCH) return;

    // Hoist weights into registers (lane-uniform values; ~252 VGPRs, 1 wave/SIMD is fine
    // since the whole problem is only 16 waves).
    float rw10[HID], rw11[HID], rb1[HID], rw20[HID], rw21[HID];
#pragma unroll
    for (int j = 0; j < HID; ++j) {
        rw10[j] = w1[2 * j + 0];   // w1[j][0]
        rw11[j] = w1[2 * j + 1];   // w1[j][1]
        rb1[j]  = b1[j];
        rw20[j] = w2[j];           // w2[0][j]
        rw21[j] = w2[HID + j];     // w2[1][j]
    }
    const float b20 = b2[0], b21 = b2[1];

    // f(h) = W2 tanh(W1 h + b1) + b2
    auto feval = [&](float hx, float hy, float& fx, float& fy) {
        float a0 = b20, a1 = b21;
#pragma unroll
        for (int j = 0; j < HID; ++j) {
            float hpre = fmaf(rw10[j], hx, fmaf(rw11[j], hy, rb1[j]));
            float th = fast_tanh(hpre);
            a0 = fmaf(rw20[j], th, a0);
            a1 = fmaf(rw21[j], th, a1);
        }
        fx = a0; fy = a1;
    };

    float x = h0[2 * b + 0];
    float y = h0[2 * b + 1];

    float2* out2 = reinterpret_cast<float2*>(out);
    out2[0 * BATCH + b] = make_float2(x, y);   // y(t[0]) = h0

    float tprev = ts[0];
    for (int i = 1; i < NT; ++i) {
        float tcur = ts[i];
        float dt = (tcur - tprev) * (1.0f / SUB);
#pragma unroll
        for (int s = 0; s < SUB; ++s) {
            float k1x, k1y, k2x, k2y, k3x, k3y, k4x, k4y;
            feval(x, y, k1x, k1y);
            feval(fmaf(0.5f * dt, k1x, x), fmaf(0.5f * dt, k1y, y), k2x, k2y);
            feval(fmaf(0.5f * dt, k2x, x), fmaf(0.5f * dt, k2y, y), k3x, k3y);
            feval(fmaf(dt, k3x, x), fmaf(dt, k3y, y), k4x, k4y);
            x += dt * (1.0f / 6.0f) * (k1x + 2.0f * k2x + 2.0f * k3x + k4x);
            y += dt * (1.0f / 6.0f) * (k1y + 2.0f * k2y + 2.0f * k3y + k4y);
        }
        out2[(size_t)i * BATCH + b] = make_float2(x, y);
        tprev = tcur;
    }
}

extern "C" void kernel_launch(void* const* d_in, const int* in_sizes, int n_in,
                              void* d_out, int out_size, void* d_ws, size_t ws_size,
                              hipStream_t stream) {
    const float* h0 = (const float*)d_in[0];
    const float* t  = (const float*)d_in[1];
    const float* w1 = (const float*)d_in[2];
    const float* b1 = (const float*)d_in[3];
    const float* w2 = (const float*)d_in[4];
    const float* b2 = (const float*)d_in[5];
    float* out = (float*)d_out;

    ode_rk4_kernel<<<BATCH / 256, 256, 0, stream>>>(h0, t, w1, b1, w2, b2, out);
}

// Round 2
// 161.672 us; speedup vs baseline: 6.4651x; 6.4651x over previous
//
#include <hip/hip_runtime.h>

#define BATCH 1024
#define HID 50
#define HIDP 64            // padded hidden (zero weights beyond 50)
#define NT 100
#define SUB 2              // RK4 substeps per output interval
#define LPE 16             // lanes per element (one DPP row)
#define UPL 4              // hidden units per lane (LPE*UPL = HIDP)

// tanh(x) = 1 - 2/(exp(2x)+1); exp(2x)=exp2(x*2*log2e). ~1e-7 abs err, exact at 0/inf.
__device__ __forceinline__ float fast_tanh(float x) {
    float e = __builtin_amdgcn_exp2f(x * 2.8853900817779268f);
    return 1.0f - 2.0f * __builtin_amdgcn_rcpf(e + 1.0f);
}

// DPP-shifted copy of x (compile-time ctrl); compiler folds into v_add_f32 dpp.
template <int CTRL>
__device__ __forceinline__ float dpp_mov(float x) {
    int xi = __builtin_bit_cast(int, x);
    int yi = __builtin_amdgcn_update_dpp(xi, xi, CTRL, 0xF, 0xF, true);
    return __builtin_bit_cast(float, yi);
}

// Reduce-sum across the 16-lane row; every lane ends with the row total.
// quad_perm[1,0,3,2]=0xB1 (xor1), quad_perm[2,3,0,1]=0x4E (xor2),
// row_ror:4=0x124, row_ror:8=0x128 (quads are uniform after the first two).
__device__ __forceinline__ float row16_reduce(float x) {
    x += dpp_mov<0xB1>(x);
    x += dpp_mov<0x4E>(x);
    x += dpp_mov<0x124>(x);
    x += dpp_mov<0x128>(x);
    return x;
}

__global__ __launch_bounds__(64)
void ode_rk4_kernel(const float* __restrict__ h0,
                    const float* __restrict__ ts,
                    const float* __restrict__ w1,
                    const float* __restrict__ b1,
                    const float* __restrict__ w2,
                    const float* __restrict__ b2,
                    float* __restrict__ out) {
    const int tid  = threadIdx.x;          // 0..63, one wave per block
    const int l    = tid & (LPE - 1);      // lane within element row
    const int erow = tid >> 4;             // element row within wave (0..3)
    const int b    = blockIdx.x * 4 + erow;

    // Per-lane weights: units j = l*UPL + u  (zero-padded past HID).
    float rw10[UPL], rw11[UPL], rb1[UPL], rw20[UPL], rw21[UPL];
#pragma unroll
    for (int u = 0; u < UPL; ++u) {
        int j = l * UPL + u;
        bool v = (j < HID);
        rw10[u] = v ? w1[2 * j + 0] : 0.0f;
        rw11[u] = v ? w1[2 * j + 1] : 0.0f;
        rb1[u]  = v ? b1[j]         : 0.0f;
        rw20[u] = v ? w2[j]         : 0.0f;
        rw21[u] = v ? w2[HID + j]   : 0.0f;
    }
    const float b20 = b2[0], b21 = b2[1];

    // f(h) = W2 tanh(W1 h + b1) + b2, cooperatively across 16 lanes.
    auto feval = [&](float hx, float hy, float& fx, float& fy) {
        float a0 = 0.0f, a1 = 0.0f;
#pragma unroll
        for (int u = 0; u < UPL; ++u) {
            float hpre = fmaf(rw10[u], hx, fmaf(rw11[u], hy, rb1[u]));
            float th = fast_tanh(hpre);
            a0 = fmaf(rw20[u], th, a0);
            a1 = fmaf(rw21[u], th, a1);
        }
        fx = row16_reduce(a0) + b20;
        fy = row16_reduce(a1) + b21;
    };

    // All 16 lanes of a row carry identical copies of the state (redundant
    // compute; reduction broadcast keeps them consistent bit-exactly).
    float x = h0[2 * b + 0];
    float y = h0[2 * b + 1];

    float2* out2 = reinterpret_cast<float2*>(out);
    if (l == 0) out2[0 * BATCH + b] = make_float2(x, y);

    float tprev = ts[0];
    for (int i = 1; i < NT; ++i) {
        float tcur = ts[i];
        float dt = (tcur - tprev) * (1.0f / SUB);
#pragma unroll
        for (int s = 0; s < SUB; ++s) {
            float k1x, k1y, k2x, k2y, k3x, k3y, k4x, k4y;
            feval(x, y, k1x, k1y);
            feval(fmaf(0.5f * dt, k1x, x), fmaf(0.5f * dt, k1y, y), k2x, k2y);
            feval(fmaf(0.5f * dt, k2x, x), fmaf(0.5f * dt, k2y, y), k3x, k3y);
            feval(fmaf(dt, k3x, x), fmaf(dt, k3y, y), k4x, k4y);
            x += dt * (1.0f / 6.0f) * (k1x + 2.0f * k2x + 2.0f * k3x + k4x);
            y += dt * (1.0f / 6.0f) * (k1y + 2.0f * k2y + 2.0f * k3y + k4y);
        }
        if (l == 0) out2[(size_t)i * BATCH + b] = make_float2(x, y);
        tprev = tcur;
    }
}

extern "C" void kernel_launch(void* const* d_in, const int* in_sizes, int n_in,
                              void* d_out, int out_size, void* d_ws, size_t ws_size,
                              hipStream_t stream) {
    const float* h0 = (const float*)d_in[0];
    const float* t  = (const float*)d_in[1];
    const float* w1 = (const float*)d_in[2];
    const float* b1 = (const float*)d_in[3];
    const float* w2 = (const float*)d_in[4];
    const float* b2 = (const float*)d_in[5];
    float* out = (float*)d_out;

    ode_rk4_kernel<<<BATCH / 4, 64, 0, stream>>>(h0, t, w1, b1, w2, b2, out);
}

// Round 3
// 114.794 us; speedup vs baseline: 9.1053x; 1.4084x over previous
//
#include <hip/hip_runtime.h>

#define BATCH 1024
#define HID 50
#define NT 100
#define LPE 16             // lanes per element (one DPP row)
#define UPL 4              // hidden units per lane (LPE*UPL = 64 >= HID, zero-padded)

// tanh(x) = 1 - 2/(exp(2x)+1); exp(2x)=exp2(x*2*log2e). ~1e-7 abs err, exact at 0/inf.
__device__ __forceinline__ float fast_tanh(float x) {
    float e = __builtin_amdgcn_exp2f(x * 2.8853900817779268f);
    return 1.0f - 2.0f * __builtin_amdgcn_rcpf(e + 1.0f);
}

template <int CTRL>
__device__ __forceinline__ float dpp_mov(float x) {
    int xi = __builtin_bit_cast(int, x);
    int yi = __builtin_amdgcn_update_dpp(xi, xi, CTRL, 0xF, 0xF, true);
    return __builtin_bit_cast(float, yi);
}

// Sum across each 16-lane row; all 16 lanes end with the row total.
// xor1 (quad_perm 0xB1), xor2 (quad_perm 0x4E), row_ror:4, row_ror:8.
__device__ __forceinline__ float row16_reduce(float x) {
    x += dpp_mov<0xB1>(x);
    x += dpp_mov<0x4E>(x);
    x += dpp_mov<0x124>(x);
    x += dpp_mov<0x128>(x);
    return x;
}

__global__ __launch_bounds__(64, 1)   // min-waves=1: allow full VGPR budget
void ode_rk4_kernel(const float* __restrict__ h0,
                    const float* __restrict__ ts,
                    const float* __restrict__ w1,
                    const float* __restrict__ b1,
                    const float* __restrict__ w2,
                    const float* __restrict__ b2,
                    float* __restrict__ out) {
    const int tid  = threadIdx.x;          // one wave per block
    const int l    = tid & (LPE - 1);      // lane within element row
    const int erow = tid >> 4;             // element row within wave (0..3)
    const int b    = blockIdx.x * 4 + erow;

    // Per-lane weights: units j = l*UPL + u (zero-padded past HID).
    float rw10[UPL], rw11[UPL], rb1[UPL], rw20[UPL], rw21[UPL];
#pragma unroll
    for (int u = 0; u < UPL; ++u) {
        int j = l * UPL + u;
        bool v = (j < HID);
        rw10[u] = v ? w1[2 * j + 0] : 0.0f;
        rw11[u] = v ? w1[2 * j + 1] : 0.0f;
        rb1[u]  = v ? b1[j]         : 0.0f;
        rw20[u] = v ? w2[j]         : 0.0f;
        rw21[u] = v ? w2[HID + j]   : 0.0f;
    }
    // Pin the 20 weight values in VGPRs: the asm "produces" them, so the
    // compiler cannot sink/rematerialize the loads into the time loop
    // (R2: VGPR_Count=20 showed it re-loaded weights every feval).
#pragma unroll
    for (int u = 0; u < UPL; ++u) {
        asm volatile("" : "+v"(rw10[u]), "+v"(rw11[u]), "+v"(rb1[u]),
                          "+v"(rw20[u]), "+v"(rw21[u]));
    }
    const float b20 = b2[0], b21 = b2[1];

    // f(h) = W2 tanh(W1 h + b1) + b2, cooperatively across 16 lanes.
    // Explicit 2-level tree accumulate for short dependency chains.
    auto feval = [&](float hx, float hy, float& fx, float& fy) {
        float th[UPL];
#pragma unroll
        for (int u = 0; u < UPL; ++u) {
            float hpre = fmaf(rw10[u], hx, fmaf(rw11[u], hy, rb1[u]));
            th[u] = fast_tanh(hpre);
        }
        float a0 = fmaf(rw20[1], th[1], rw20[0] * th[0])
                 + fmaf(rw20[3], th[3], rw20[2] * th[2]);
        float a1 = fmaf(rw21[1], th[1], rw21[0] * th[0])
                 + fmaf(rw21[3], th[3], rw21[2] * th[2]);
        fx = row16_reduce(a0) + b20;
        fy = row16_reduce(a1) + b21;
    };

    float x = h0[2 * b + 0];
    float y = h0[2 * b + 1];

    float2* out2 = reinterpret_cast<float2*>(out);
    if (l == 0) out2[0 * BATCH + b] = make_float2(x, y);

    float tprev = ts[0];
    float tnext = ts[1];
    for (int i = 1; i < NT; ++i) {
        float tcur = tnext;
        tnext = ts[(i + 1 < NT) ? (i + 1) : (NT - 1)];   // prefetch off-chain
        float dt = tcur - tprev;                          // one RK4 step per interval

        float k1x, k1y, k2x, k2y, k3x, k3y, k4x, k4y;
        feval(x, y, k1x, k1y);
        feval(fmaf(0.5f * dt, k1x, x), fmaf(0.5f * dt, k1y, y), k2x, k2y);
        feval(fmaf(0.5f * dt, k2x, x), fmaf(0.5f * dt, k2y, y), k3x, k3y);
        feval(fmaf(dt, k3x, x), fmaf(dt, k3y, y), k4x, k4y);
        x += dt * (1.0f / 6.0f) * (k1x + 2.0f * k2x + 2.0f * k3x + k4x);
        y += dt * (1.0f / 6.0f) * (k1y + 2.0f * k2y + 2.0f * k3y + k4y);

        if (l == 0) out2[(size_t)i * BATCH + b] = make_float2(x, y);
        tprev = tcur;
    }
}

extern "C" void kernel_launch(void* const* d_in, const int* in_sizes, int n_in,
                              void* d_out, int out_size, void* d_ws, size_t ws_size,
                              hipStream_t stream) {
    const float* h0 = (const float*)d_in[0];
    const float* t  = (const float*)d_in[1];
    const float* w1 = (const float*)d_in[2];
    const float* b1 = (const float*)d_in[3];
    const float* w2 = (const float*)d_in[4];
    const float* b2 = (const float*)d_in[5];
    float* out = (float*)d_out;

    ode_rk4_kernel<<<BATCH / 4, 64, 0, stream>>>(h0, t, w1, b1, w2, b2, out);
}